// Round 7
// baseline (129.531 us; speedup 1.0000x reference)
//
#include <hip/hip_runtime.h>
#include <hip/hip_bf16.h>
#include <stdint.h>

#define NHEADS 12
#define HS 64
#define NB 8
#define NL 1024
#define ND 768
#define NE 1536
#define INFV 1000000000000.0f

typedef __bf16 bf16x8 __attribute__((ext_vector_type(8)));
typedef float f32x4 __attribute__((ext_vector_type(4)));

typedef __attribute__((address_space(1))) const unsigned int gas_uint;
typedef __attribute__((address_space(3))) unsigned int las_uint;
#define GLOAD_LDS16(g, l) __builtin_amdgcn_global_load_lds((gas_uint*)(g), (las_uint*)(l), 16, 0, 0)

__device__ __forceinline__ unsigned short f2bf(float f) {
  unsigned int u = __builtin_bit_cast(unsigned int, f);
  u += 0x7fffu + ((u >> 16) & 1u);   // round-to-nearest-even
  return (unsigned short)(u >> 16);
}

__device__ __forceinline__ bf16x8 load_frag(const unsigned short* p) {
  uint4 v = *(const uint4*)p;
  return __builtin_bit_cast(bf16x8, v);
}

// ---- prep: W transpose->bf16 | rope trig table (x-cvt fused into proj) ----
// cst: [1024 pos] rows of 64 floats: (cos_i, sin_i) pairs for si=0..31.
__global__ __launch_bounds__(256) void k_prep(
    const float* __restrict__ W,
    unsigned short* __restrict__ wt,
    float* __restrict__ cst) {
  const int blk = blockIdx.x;
  if (blk < 288) {
    __shared__ float tile[64][65];
    int te = blk % 24, td = blk / 24;
    int c = threadIdx.x & 63, r4 = threadIdx.x >> 6;
    #pragma unroll
    for (int rr = 0; rr < 16; rr++) {
      int row = rr * 4 + r4;
      tile[row][c] = W[(size_t)(td * 64 + row) * NE + te * 64 + c];
    }
    __syncthreads();
    #pragma unroll
    for (int rr = 0; rr < 16; rr++) {
      int row = rr * 4 + r4;
      wt[(size_t)(te * 64 + row) * ND + td * 64 + c] = f2bf(tile[c][row]);
    }
  } else {
    int t = (blk - 288) * 256 + threadIdx.x;   // 32768 = 1024*32
    int p = t >> 5, i = t & 31;
    float inv = powf(10000.0f, -(float)i / 32.0f);
    float sv, cv;
    sincosf((float)p * inv, &sv, &cv);
    cst[(p * 32 + i) * 2 + 0] = cv;
    cst[(p * 32 + i) * 2 + 1] = sv;
  }
}

// ---- proj GEMM (x @ W + b) + RoPE — LDS staging; x staged as fp32 ----
// A (W^T, bf16): [128e][64k] @ 0, 16 KB, 8 slots/row, phys = s ^ (r&7).
// B (x, fp32):   [128m][64k] @ 16384, 32 KB, 16 slots/row, phys = s ^ (r&15).
// Both pre-swizzled at the GLOBAL source (linear gload_lds dest, rule #21).
// Flat grid 768, XCD-grouped: 12 h-blocks per m-tile on one XCD (x L2 reuse).
__global__ __launch_bounds__(256) void k_proj_rope(
    const float* __restrict__ x,             // [8192][768] fp32
    const unsigned short* __restrict__ wt,   // [1536][768] bf16 (W^T)
    const float* __restrict__ bias,          // [1536]
    const float* __restrict__ cst,           // [1024][64] (c,s) pairs
    unsigned short* __restrict__ qbuf, unsigned short* __restrict__ kbuf) {
  const int blk = blockIdx.x;
  const int xcd = blk & 7;
  const int loc = blk >> 3;
  const int h   = loc % 12;
  const int mt  = xcd * 8 + loc / 12;
  const int m0  = mt * 128;
  const int e0  = h * 128;
  const int tid  = threadIdx.x;
  const int lane = tid & 63;
  const int w    = tid >> 6;
  const int wm = w >> 1, wn = w & 1;
  const int col_l = lane & 15, rq = lane >> 4;

  __shared__ char smem_b[49152];             // A 16K | B 32K

  // A staging: 1024 16B chunks, 4/thread
  unsigned int goffA[4];
  #pragma unroll
  for (int q = 0; q < 4; q++) {
    int p = q * 256 + tid;
    int r = p >> 3, sl = p & 7;
    goffA[q] = r * ND + (sl ^ (r & 7)) * 8;  // bf16 elements
  }
  // B staging: 2048 16B chunks, 8/thread
  unsigned int goffB[8];
  #pragma unroll
  for (int q = 0; q < 8; q++) {
    int p = q * 256 + tid;
    int r = p >> 4, sl = p & 15;
    goffB[q] = r * ND + (sl ^ (r & 15)) * 4; // fp32 elements
  }
  const unsigned short* gA = wt + (size_t)e0 * ND;
  const float*          gB = x  + (size_t)m0 * ND;

  // A ds_read addrs: row RA = wn*64 + f*16 + col_l (RA&7 == col_l&7)
  const int xr = col_l & 7;
  const unsigned int aRow = (unsigned)((wn * 64 + col_l) * 128);
  // B ds_read addrs: row RB = wm*64 + f*16 + col_l (RB&15 == col_l)
  const unsigned int bRow = (unsigned)(16384 + (wm * 64 + col_l) * 256);

  f32x4 acc[4][4];   // [e-frag][m-frag]
  #pragma unroll
  for (int i = 0; i < 4; i++)
    #pragma unroll
    for (int j = 0; j < 4; j++)
      #pragma unroll
      for (int q = 0; q < 4; q++) acc[i][j][q] = 0.0f;

  for (int kk = 0; kk < ND; kk += 64) {
    const unsigned short* sA = gA + kk;
    const float*          sB = gB + kk;
    #pragma unroll
    for (int q = 0; q < 4; q++) GLOAD_LDS16(sA + goffA[q], smem_b + (q * 256 + tid) * 16);
    #pragma unroll
    for (int q = 0; q < 8; q++) GLOAD_LDS16(sB + goffB[q], smem_b + 16384 + (q * 256 + tid) * 16);
    __syncthreads();
    #pragma unroll
    for (int kkh = 0; kkh < 2; kkh++) {
      bf16x8 af[4], bfr[4];
      #pragma unroll
      for (int f = 0; f < 4; f++) {
        af[f] = __builtin_bit_cast(bf16x8,
            *(const uint4*)(smem_b + aRow + f * 2048 + (((kkh << 2) | rq) ^ xr) * 16));
        const int sl0 = (kkh << 3) | (rq << 1);
        float4 lo = *(const float4*)(smem_b + bRow + f * 4096 + ((sl0 ^ col_l) * 16));
        float4 hi = *(const float4*)(smem_b + bRow + f * 4096 + (((sl0 + 1) ^ col_l) * 16));
        bfr[f] = bf16x8{(__bf16)lo.x, (__bf16)lo.y, (__bf16)lo.z, (__bf16)lo.w,
                        (__bf16)hi.x, (__bf16)hi.y, (__bf16)hi.z, (__bf16)hi.w};
      }
      #pragma unroll
      for (int i = 0; i < 4; i++)
        #pragma unroll
        for (int j = 0; j < 4; j++)
          acc[i][j] = __builtin_amdgcn_mfma_f32_16x16x32_bf16(af[i], bfr[j], acc[i][j], 0, 0, 0);
    }
    __syncthreads();
  }

  // epilogue: bias + rope (in-thread pairs; one 16B trig load per frag)
  unsigned short* obuf = (wn == 1) ? kbuf : qbuf;   // wave-uniform
  #pragma unroll
  for (int j = 0; j < 4; j++) {
    const int m   = m0 + wm * 64 + j * 16 + col_l;
    const int pos = m & (NL - 1);
    const int bb  = m >> 10;
    const float* crow = cst + pos * 64;
    unsigned short* orow = obuf + (((size_t)(bb * NHEADS + h)) * NL + pos) * HS;
    #pragma unroll
    for (int i = 0; i < 4; i++) {
      const int s0 = i * 16 + rq * 4;
      float4 bv = *(const float4*)&bias[e0 + wn * 64 + s0];
      float4 tq = *(const float4*)(crow + s0);  // (c,s) for si0 | (c,s) for si0+1
      float v0 = acc[i][j][0] + bv.x;
      float v1 = acc[i][j][1] + bv.y;
      float v2 = acc[i][j][2] + bv.z;
      float v3 = acc[i][j][3] + bv.w;
      ushort4 o;
      o.x = f2bf(v0 * tq.x - v1 * tq.y);
      o.y = f2bf(v1 * tq.x + v0 * tq.y);
      o.z = f2bf(v2 * tq.z - v3 * tq.w);
      o.w = f2bf(v3 * tq.z + v2 * tq.w);
      *(ushort4*)&orow[s0] = o;
    }
  }
}

// ---- logits: per (b,h) Q @ K^T with masks, /8 ----
// XCD-grouped flat grid; below-diag tiles -> fill path; compute tiles
// use an LDS-bounce epilogue with 512B-contiguous NT stores.
__global__ __launch_bounds__(256) void k_logits(
    const unsigned short* __restrict__ qbuf,
    const unsigned short* __restrict__ kbuf,
    const int* __restrict__ mask,
    float* __restrict__ out) {
  const int f  = blockIdx.x;
  const int r  = f & 7, t = f >> 3;
  const int bh = r + 8 * (t >> 6);           // 12 heads per XCD residue
  const int tile = t & 63;
  const int tm = tile >> 3, tn = tile & 7;
  const int b  = bh / NHEADS;
  const int tid  = threadIdx.x;
  const int* mrow = mask + b * NL;

  if (tn < tm) {
    const int n0 = tn * 128 + (tid & 31) * 4;
    int4 mc = *(const int4*)&mrow[n0];
    #pragma unroll
    for (int it = 0; it < 16; it++) {
      int m = tm * 128 + it * 8 + (tid >> 5);
      float mr = (float)mrow[m];
      float base = -INFV * (1.0f - mr);      // v*mr with v=0
      f32x4 o;
      o[0] = ((mc.x ? base : -INFV) - INFV) * 0.125f;
      o[1] = ((mc.y ? base : -INFV) - INFV) * 0.125f;
      o[2] = ((mc.z ? base : -INFV) - INFV) * 0.125f;
      o[3] = ((mc.w ? base : -INFV) - INFV) * 0.125f;
      __builtin_nontemporal_store(o, (f32x4*)(out + ((size_t)bh * NL + m) * NL + n0));
    }
    return;
  }

  const int lane = tid & 63;
  const int w    = tid >> 6;
  const int wm = w >> 1, wn = w & 1;
  const int m_base = tm * 128 + wm * 64;
  const int n_base = tn * 128 + wn * 64;
  const int col_l = lane & 15, rq = lane >> 4;
  const unsigned short* Q = qbuf + (size_t)bh * (NL * HS);
  const unsigned short* K = kbuf + (size_t)bh * (NL * HS);

  __shared__ float lds[64 * 132];            // +4 float row pad

  f32x4 acc[4][4];   // [n-frag][m-frag]
  #pragma unroll
  for (int i = 0; i < 4; i++)
    #pragma unroll
    for (int j = 0; j < 4; j++)
      #pragma unroll
      for (int q = 0; q < 4; q++) acc[i][j][q] = 0.0f;

  #pragma unroll
  for (int ks = 0; ks < 2; ks++) {
    bf16x8 ak[4], bq[4];
    #pragma unroll
    for (int ff = 0; ff < 4; ff++) {
      ak[ff] = load_frag(K + (size_t)(n_base + ff * 16 + col_l) * HS + ks * 32 + rq * 8);
      bq[ff] = load_frag(Q + (size_t)(m_base + ff * 16 + col_l) * HS + ks * 32 + rq * 8);
    }
    #pragma unroll
    for (int i = 0; i < 4; i++)
      #pragma unroll
      for (int j = 0; j < 4; j++)
        acc[i][j] = __builtin_amdgcn_mfma_f32_16x16x32_bf16(ak[i], bq[j], acc[i][j], 0, 0, 0);
  }

  const bool diag = (tn == tm);
  const int rb_row = tid >> 5;
  const int rb_c4  = (tid & 31) * 4;
  const int n_rb   = tn * 128 + rb_c4;
  int4 mc_rb = *(const int4*)&mrow[n_rb];
  const bool allmc = (mc_rb.x & mc_rb.y & mc_rb.z & mc_rb.w) != 0;

  #pragma unroll
  for (int pass = 0; pass < 2; pass++) {
    if (wm == pass) {
      #pragma unroll
      for (int j = 0; j < 4; j++) {
        const int rl = j * 16 + col_l;
        #pragma unroll
        for (int i = 0; i < 4; i++)
          *(f32x4*)&lds[rl * 132 + wn * 64 + i * 16 + rq * 4] = acc[i][j];
      }
    }
    __syncthreads();
    #pragma unroll
    for (int it = 0; it < 8; it++) {
      const int rl = it * 8 + rb_row;
      const int m  = tm * 128 + pass * 64 + rl;
      f32x4 v = *(const f32x4*)&lds[rl * 132 + rb_c4];
      if (mrow[m] == 0) { v[0] = -INFV; v[1] = -INFV; v[2] = -INFV; v[3] = -INFV; }
      if (!allmc) {
        if (mc_rb.x == 0) v[0] = -INFV;
        if (mc_rb.y == 0) v[1] = -INFV;
        if (mc_rb.z == 0) v[2] = -INFV;
        if (mc_rb.w == 0) v[3] = -INFV;
      }
      if (diag) {
        if (n_rb + 0 < m) v[0] -= INFV;
        if (n_rb + 1 < m) v[1] -= INFV;
        if (n_rb + 2 < m) v[2] -= INFV;
        if (n_rb + 3 < m) v[3] -= INFV;
      }
      v *= 0.125f;
      __builtin_nontemporal_store(v, (f32x4*)(out + ((size_t)bh * NL + m) * NL + n_rb));
    }
    __syncthreads();
  }
}

extern "C" void kernel_launch(void* const* d_in, const int* in_sizes, int n_in,
                              void* d_out, int out_size, void* d_ws, size_t ws_size,
                              hipStream_t stream) {
  const float* x    = (const float*)d_in[0];
  const float* W    = (const float*)d_in[1];
  const float* bias = (const float*)d_in[2];
  const int*   mask = (const int*)d_in[3];
  float* out = (float*)d_out;
  char* ws = (char*)d_ws;

  unsigned short* wt = (unsigned short*)(ws);              //  2,359,296 B
  unsigned short* qb = (unsigned short*)(ws + 2359296);    // 12,582,912 B
  unsigned short* kb = (unsigned short*)(ws + 14942208);   // 12,582,912 B
  float* cst = (float*)(ws + 27525120);                    //    262,144 B

  k_prep<<<416, 256, 0, stream>>>(W, wt, cst);
  k_proj_rope<<<768, 256, 0, stream>>>(x, wt, bias, cst, qb, kb);
  k_logits<<<6144, 256, 0, stream>>>(qb, kb, mask, out);
}

// Round 8
// 126.991 us; speedup vs baseline: 1.0200x; 1.0200x over previous
//
#include <hip/hip_runtime.h>
#include <hip/hip_bf16.h>
#include <stdint.h>

#define NHEADS 12
#define HS 64
#define NB 8
#define NL 1024
#define ND 768
#define NE 1536
#define INFV 1000000000000.0f

typedef __bf16 bf16x8 __attribute__((ext_vector_type(8)));
typedef float f32x4 __attribute__((ext_vector_type(4)));

typedef __attribute__((address_space(1))) const unsigned int gas_uint;
typedef __attribute__((address_space(3))) unsigned int las_uint;
#define GLOAD_LDS16(g, l) __builtin_amdgcn_global_load_lds((gas_uint*)(g), (las_uint*)(l), 16, 0, 0)

__device__ __forceinline__ unsigned short f2bf(float f) {
  unsigned int u = __builtin_bit_cast(unsigned int, f);
  u += 0x7fffu + ((u >> 16) & 1u);   // round-to-nearest-even
  return (unsigned short)(u >> 16);
}

__device__ __forceinline__ bf16x8 load_frag(const unsigned short* p) {
  uint4 v = *(const uint4*)p;
  return __builtin_bit_cast(bf16x8, v);
}

// one below-diagonal fill store: idx indexes [2688 tiles][128 rows][32 f32x4]
// value = full mask arithmetic with v=0 (exact for causally-masked entries
// up to |v|/8 <= ~4, vs threshold 2.5e9).
__device__ __forceinline__ void do_fill(int idx, const int* __restrict__ mask,
                                        float* __restrict__ out) {
  int t   = idx >> 12;
  int w   = idx & 4095;
  int row = w >> 5, cg = w & 31;
  int bh  = t / 28;
  int t28 = t - bh * 28;
  float ft = sqrtf(8.0f * (float)t28 + 1.0f);
  int tm = (int)((1.0f + ft) * 0.5f);
  if (t28 < ((tm * (tm - 1)) >> 1)) tm--;
  else if (t28 >= ((tm * (tm + 1)) >> 1)) tm++;
  int tn = t28 - ((tm * (tm - 1)) >> 1);     // tn < tm guaranteed
  int b  = bh / NHEADS;
  int m  = tm * 128 + row;
  const int* mrow = mask + b * NL;
  float mr = (float)mrow[m];
  int4 mc  = *(const int4*)&mrow[tn * 128 + cg * 4];
  float base = -INFV * (1.0f - mr);
  f32x4 o;
  o[0] = ((mc.x ? base : -INFV) - INFV) * 0.125f;
  o[1] = ((mc.y ? base : -INFV) - INFV) * 0.125f;
  o[2] = ((mc.z ? base : -INFV) - INFV) * 0.125f;
  o[3] = ((mc.w ? base : -INFV) - INFV) * 0.125f;
  __builtin_nontemporal_store(o, (f32x4*)(out + ((size_t)bh * NL + m) * NL + tn * 128 + cg * 4));
}

// ---- prep: W transpose->bf16 | rope trig table ----
__global__ __launch_bounds__(256) void k_prep(
    const float* __restrict__ W,
    unsigned short* __restrict__ wt,
    float* __restrict__ cst) {
  const int blk = blockIdx.x;
  if (blk < 288) {
    __shared__ float tile[64][65];
    int te = blk % 24, td = blk / 24;
    int c = threadIdx.x & 63, r4 = threadIdx.x >> 6;
    #pragma unroll
    for (int rr = 0; rr < 16; rr++) {
      int row = rr * 4 + r4;
      tile[row][c] = W[(size_t)(td * 64 + row) * NE + te * 64 + c];
    }
    __syncthreads();
    #pragma unroll
    for (int rr = 0; rr < 16; rr++) {
      int row = rr * 4 + r4;
      wt[(size_t)(te * 64 + row) * ND + td * 64 + c] = f2bf(tile[c][row]);
    }
  } else {
    int t = (blk - 288) * 256 + threadIdx.x;   // 32768 = 1024*32
    int p = t >> 5, i = t & 31;
    float inv = powf(10000.0f, -(float)i / 32.0f);
    float sv, cv;
    sincosf((float)p * inv, &sv, &cv);
    cst[(p * 32 + i) * 2 + 0] = cv;
    cst[(p * 32 + i) * 2 + 1] = sv;
  }
}

// ---- proj GEMM (x @ W + b) + RoPE, with below-diag fill stores woven in ----
// A (W^T, bf16): [128e][64k] @ 0, 16 KB. B (x, fp32): [128m][64k] @ 16384, 32 KB.
// Each block also emits 14336 fill f32x4s (56/thread), 5 or 4 per K-step,
// issued at the top of the compute phase so they stream under MFMA/ds_read.
__global__ __launch_bounds__(256) void k_proj_rope(
    const float* __restrict__ x,             // [8192][768] fp32
    const unsigned short* __restrict__ wt,   // [1536][768] bf16 (W^T)
    const float* __restrict__ bias,          // [1536]
    const float* __restrict__ cst,           // [1024][32] float2 (c,s)
    unsigned short* __restrict__ qbuf, unsigned short* __restrict__ kbuf,
    const int* __restrict__ mask, float* __restrict__ out) {
  const int blk = blockIdx.x;
  const int xcd = blk & 7;
  const int loc = blk >> 3;
  const int h   = loc % 12;
  const int mt  = xcd * 8 + loc / 12;
  const int m0  = mt * 128;
  const int e0  = h * 128;
  const int tid  = threadIdx.x;
  const int lane = tid & 63;
  const int w    = tid >> 6;
  const int wm = w >> 1, wn = w & 1;
  const int col_l = lane & 15, rq = lane >> 4;
  const int fill_base = blk * 14336 + tid;

  __shared__ char smem_b[49152];             // A 16K | B 32K

  unsigned int goffA[4];
  #pragma unroll
  for (int q = 0; q < 4; q++) {
    int p = q * 256 + tid;
    int r = p >> 3, sl = p & 7;
    goffA[q] = r * ND + (sl ^ (r & 7)) * 8;  // bf16 elements
  }
  unsigned int goffB[8];
  #pragma unroll
  for (int q = 0; q < 8; q++) {
    int p = q * 256 + tid;
    int r = p >> 4, sl = p & 15;
    goffB[q] = r * ND + (sl ^ (r & 15)) * 4; // fp32 elements
  }
  const unsigned short* gA = wt + (size_t)e0 * ND;
  const float*          gB = x  + (size_t)m0 * ND;

  const int xr = col_l & 7;
  const unsigned int aRow = (unsigned)((wn * 64 + col_l) * 128);
  const unsigned int bRow = (unsigned)(16384 + (wm * 64 + col_l) * 256);

  f32x4 acc[4][4];   // [e-frag][m-frag]
  #pragma unroll
  for (int i = 0; i < 4; i++)
    #pragma unroll
    for (int j = 0; j < 4; j++)
      #pragma unroll
      for (int q = 0; q < 4; q++) acc[i][j][q] = 0.0f;

  int step = 0;
  for (int kk = 0; kk < ND; kk += 64, step++) {
    const unsigned short* sA = gA + kk;
    const float*          sB = gB + kk;
    #pragma unroll
    for (int q = 0; q < 4; q++) GLOAD_LDS16(sA + goffA[q], smem_b + (q * 256 + tid) * 16);
    #pragma unroll
    for (int q = 0; q < 8; q++) GLOAD_LDS16(sB + goffB[q], smem_b + 16384 + (q * 256 + tid) * 16);
    __syncthreads();
    // weave fill stores into the compute phase (independent, stream under MFMA)
    {
      const int nst = (step < 8) ? 5 : 4;
      const int sb  = (step < 8) ? step * 5 : 40 + (step - 8) * 4;
      for (int q = 0; q < nst; q++) do_fill(fill_base + (sb + q) * 256, mask, out);
    }
    #pragma unroll
    for (int kkh = 0; kkh < 2; kkh++) {
      bf16x8 af[4], bfr[4];
      #pragma unroll
      for (int f = 0; f < 4; f++) {
        af[f] = __builtin_bit_cast(bf16x8,
            *(const uint4*)(smem_b + aRow + f * 2048 + (((kkh << 2) | rq) ^ xr) * 16));
        const int sl0 = (kkh << 3) | (rq << 1);
        float4 lo = *(const float4*)(smem_b + bRow + f * 4096 + ((sl0 ^ col_l) * 16));
        float4 hi = *(const float4*)(smem_b + bRow + f * 4096 + (((sl0 + 1) ^ col_l) * 16));
        bfr[f] = bf16x8{(__bf16)lo.x, (__bf16)lo.y, (__bf16)lo.z, (__bf16)lo.w,
                        (__bf16)hi.x, (__bf16)hi.y, (__bf16)hi.z, (__bf16)hi.w};
      }
      #pragma unroll
      for (int i = 0; i < 4; i++)
        #pragma unroll
        for (int j = 0; j < 4; j++)
          acc[i][j] = __builtin_amdgcn_mfma_f32_16x16x32_bf16(af[i], bfr[j], acc[i][j], 0, 0, 0);
    }
    __syncthreads();
  }

  // epilogue: bias + rope (in-thread pairs; one 16B trig load per frag)
  unsigned short* obuf = (wn == 1) ? kbuf : qbuf;   // wave-uniform
  #pragma unroll
  for (int j = 0; j < 4; j++) {
    const int m   = m0 + wm * 64 + j * 16 + col_l;
    const int pos = m & (NL - 1);
    const int bb  = m >> 10;
    const float* crow = cst + pos * 64;
    unsigned short* orow = obuf + (((size_t)(bb * NHEADS + h)) * NL + pos) * HS;
    #pragma unroll
    for (int i = 0; i < 4; i++) {
      const int s0 = i * 16 + rq * 4;
      float4 bv = *(const float4*)&bias[e0 + wn * 64 + s0];
      float4 tq = *(const float4*)(crow + s0);
      float v0 = acc[i][j][0] + bv.x;
      float v1 = acc[i][j][1] + bv.y;
      float v2 = acc[i][j][2] + bv.z;
      float v3 = acc[i][j][3] + bv.w;
      ushort4 o;
      o.x = f2bf(v0 * tq.x - v1 * tq.y);
      o.y = f2bf(v1 * tq.x + v0 * tq.y);
      o.z = f2bf(v2 * tq.z - v3 * tq.w);
      o.w = f2bf(v3 * tq.z + v2 * tq.w);
      *(ushort4*)&orow[s0] = o;
    }
  }
}

// ---- logits: upper-triangle (tn >= tm) tiles only, per (b,h) Q @ K^T ----
// XCD-grouped flat grid (36 tiles x 12 heads per XCD residue).
__global__ __launch_bounds__(256) void k_logits(
    const unsigned short* __restrict__ qbuf,
    const unsigned short* __restrict__ kbuf,
    const int* __restrict__ mask,
    float* __restrict__ out) {
  const int f  = blockIdx.x;
  const int r  = f & 7, t = f >> 3;
  const int bh = r + 8 * (t / 36);
  int u = t % 36;
  int tm = 0;
  #pragma unroll
  for (int k = 0; k < 7; k++) if (u >= 8 - tm) { u -= 8 - tm; tm++; }
  const int tn = tm + u;
  const int b  = bh / NHEADS;
  const int tid  = threadIdx.x;
  const int* mrow = mask + b * NL;

  const int lane = tid & 63;
  const int w    = tid >> 6;
  const int wm = w >> 1, wn = w & 1;
  const int m_base = tm * 128 + wm * 64;
  const int n_base = tn * 128 + wn * 64;
  const int col_l = lane & 15, rq = lane >> 4;
  const unsigned short* Q = qbuf + (size_t)bh * (NL * HS);
  const unsigned short* K = kbuf + (size_t)bh * (NL * HS);

  __shared__ float lds[64 * 132];            // +4 float row pad

  f32x4 acc[4][4];   // [n-frag][m-frag]
  #pragma unroll
  for (int i = 0; i < 4; i++)
    #pragma unroll
    for (int j = 0; j < 4; j++)
      #pragma unroll
      for (int q = 0; q < 4; q++) acc[i][j][q] = 0.0f;

  #pragma unroll
  for (int ks = 0; ks < 2; ks++) {
    bf16x8 ak[4], bq[4];
    #pragma unroll
    for (int ff = 0; ff < 4; ff++) {
      ak[ff] = load_frag(K + (size_t)(n_base + ff * 16 + col_l) * HS + ks * 32 + rq * 8);
      bq[ff] = load_frag(Q + (size_t)(m_base + ff * 16 + col_l) * HS + ks * 32 + rq * 8);
    }
    #pragma unroll
    for (int i = 0; i < 4; i++)
      #pragma unroll
      for (int j = 0; j < 4; j++)
        acc[i][j] = __builtin_amdgcn_mfma_f32_16x16x32_bf16(ak[i], bq[j], acc[i][j], 0, 0, 0);
  }

  const bool diag = (tn == tm);
  const int rb_row = tid >> 5;
  const int rb_c4  = (tid & 31) * 4;
  const int n_rb   = tn * 128 + rb_c4;
  int4 mc_rb = *(const int4*)&mrow[n_rb];
  const bool allmc = (mc_rb.x & mc_rb.y & mc_rb.z & mc_rb.w) != 0;

  #pragma unroll
  for (int pass = 0; pass < 2; pass++) {
    if (wm == pass) {
      #pragma unroll
      for (int j = 0; j < 4; j++) {
        const int rl = j * 16 + col_l;
        #pragma unroll
        for (int i = 0; i < 4; i++)
          *(f32x4*)&lds[rl * 132 + wn * 64 + i * 16 + rq * 4] = acc[i][j];
      }
    }
    __syncthreads();
    #pragma unroll
    for (int it = 0; it < 8; it++) {
      const int rl = it * 8 + rb_row;
      const int m  = tm * 128 + pass * 64 + rl;
      f32x4 v = *(const f32x4*)&lds[rl * 132 + rb_c4];
      if (mrow[m] == 0) { v[0] = -INFV; v[1] = -INFV; v[2] = -INFV; v[3] = -INFV; }
      if (!allmc) {
        if (mc_rb.x == 0) v[0] = -INFV;
        if (mc_rb.y == 0) v[1] = -INFV;
        if (mc_rb.z == 0) v[2] = -INFV;
        if (mc_rb.w == 0) v[3] = -INFV;
      }
      if (diag) {
        if (n_rb + 0 < m) v[0] -= INFV;
        if (n_rb + 1 < m) v[1] -= INFV;
        if (n_rb + 2 < m) v[2] -= INFV;
        if (n_rb + 3 < m) v[3] -= INFV;
      }
      v *= 0.125f;
      __builtin_nontemporal_store(v, (f32x4*)(out + ((size_t)bh * NL + m) * NL + n_rb));
    }
    __syncthreads();
  }
}

extern "C" void kernel_launch(void* const* d_in, const int* in_sizes, int n_in,
                              void* d_out, int out_size, void* d_ws, size_t ws_size,
                              hipStream_t stream) {
  const float* x    = (const float*)d_in[0];
  const float* W    = (const float*)d_in[1];
  const float* bias = (const float*)d_in[2];
  const int*   mask = (const int*)d_in[3];
  float* out = (float*)d_out;
  char* ws = (char*)d_ws;

  unsigned short* wt = (unsigned short*)(ws);              //  2,359,296 B
  unsigned short* qb = (unsigned short*)(ws + 2359296);    // 12,582,912 B
  unsigned short* kb = (unsigned short*)(ws + 14942208);   // 12,582,912 B
  float* cst = (float*)(ws + 27525120);                    //    262,144 B

  k_prep<<<416, 256, 0, stream>>>(W, wt, cst);
  k_proj_rope<<<768, 256, 0, stream>>>(x, wt, bias, cst, qb, kb, mask, out);
  k_logits<<<3456, 256, 0, stream>>>(qb, kb, mask, out);
}